// Round 1
// baseline (243.580 us; speedup 1.0000x reference)
//
#include <hip/hip_runtime.h>
#include <hip/hip_bf16.h>

// Problem constants (match reference setup_inputs)
#define BB   64
#define CIN  2048
#define COUT 2048
#define TT   128

typedef _Float16 half8 __attribute__((ext_vector_type(8)));
typedef _Float16 half4 __attribute__((ext_vector_type(4)));
typedef float    f32x4 __attribute__((ext_vector_type(4)));

// XOR swizzle of 16B chunks within a 64B row: keeps global_load_lds staging
// (wave-uniform base + lane*16, no padding allowed) compatible with
// conflict-light ds_read_b128 fragment reads (2-way = free on gfx950).
#define SWZ(r) ((((r) & 3) ^ (((r) >> 2) & 3)))

__device__ __forceinline__ void async16(char* lds_dst, const _Float16* g_src) {
    __builtin_amdgcn_global_load_lds(
        (const __attribute__((address_space(1))) void*)g_src,
        (__attribute__((address_space(3))) void*)lds_dst,
        16, 0, 0);
}

// --- Kernel 1: masked weights -> fp16, [COUT][CIN] (B^T layout for GEMM) ---
__global__ void prep_w_kernel(const float* __restrict__ w,
                              const float* __restrict__ msk,
                              _Float16* __restrict__ out) {
    size_t i = ((size_t)blockIdx.x * 256 + threadIdx.x) * 8;
    float4 a0 = *(const float4*)(w + i);
    float4 a1 = *(const float4*)(w + i + 4);
    float4 m0 = *(const float4*)(msk + i);
    float4 m1 = *(const float4*)(msk + i + 4);
    half8 v;
    v[0] = (_Float16)(a0.x * m0.x); v[1] = (_Float16)(a0.y * m0.y);
    v[2] = (_Float16)(a0.z * m0.z); v[3] = (_Float16)(a0.w * m0.w);
    v[4] = (_Float16)(a1.x * m1.x); v[5] = (_Float16)(a1.y * m1.y);
    v[6] = (_Float16)(a1.z * m1.z); v[7] = (_Float16)(a1.w * m1.w);
    *(half8*)(out + i) = v;
}

// --- Kernel 2: spikes [B][C][T] fp32 -> A[(b*T+t)][c] fp16 (LDS transpose) ---
__global__ void prep_a_kernel(const float* __restrict__ spikes,
                              _Float16* __restrict__ A) {
    int bid = blockIdx.x;
    int cc = bid & 31;          // c-tile: 64 channels
    int tt = (bid >> 5) & 3;    // t-tile: 32 timesteps
    int b  = bid >> 7;
    int c0 = cc * 64, t0 = tt * 32;
    __shared__ float tile[64][33];

    int tid = threadIdx.x;
    int t  = tid & 31;
    int c8 = tid >> 5;          // 0..7
#pragma unroll
    for (int s = 0; s < 8; ++s) {
        int c = s * 8 + c8;
        tile[c][t] = spikes[((size_t)b * CIN + c0 + c) * TT + t0 + t];
    }
    __syncthreads();

    int tw_ = tid >> 4;         // 0..15
    int cq  = tid & 15;         // 4 channels each
#pragma unroll
    for (int s2 = 0; s2 < 2; ++s2) {
        int tw = tw_ + s2 * 16;
        half4 v;
#pragma unroll
        for (int q = 0; q < 4; ++q) v[q] = (_Float16)tile[cq * 4 + q][tw];
        *(half4*)(A + ((size_t)(b * TT) + t0 + tw) * CIN + c0 + cq * 4) = v;
    }
}

// --- Kernel 3: fused GEMM (128x128 tile, BK=32, mfma_f32_16x16x32_f16)
//     + LIF scan epilogue (fire/reset over t) + bit-packed coalesced store ---
__global__ void __launch_bounds__(256, 2)
snn_gemm_scan(const _Float16* __restrict__ A,   // [8192][2048]
              const _Float16* __restrict__ Wm,  // [2048][2048]
              const int* __restrict__ scale_exp,
              const int* __restrict__ thr_exp,
              float* __restrict__ out) {        // [B][COUT][T]
    __shared__ __align__(16) union {
        struct { _Float16 a[128 * 32]; _Float16 b[128 * 32]; } st; // 16 KB
        float c[128 * 132];                                        // 66 KB
    } lds;
    __shared__ unsigned pb[128 * 4];

    const int tid  = threadIdx.x;
    const int lane = tid & 63;
    const int w    = tid >> 6;

    // XCD-aware swizzle: blocks on one XCD share b -> A-tile L2 reuse
    int flat = blockIdx.x;
    int xcd = flat & 7, idx = flat >> 3;
    int b  = xcd * 8 + (idx >> 4);
    int n0 = (idx & 15) * 128;
    int m0 = b * TT;

    // staging: 512 chunks/tile of 16B, 2 per thread, swizzled placement
    int p0 = tid, p1 = tid + 256;
    int r0 = p0 >> 2, r1 = p1 >> 2;
    int c0g = (p0 & 3) ^ SWZ(r0);
    int c1g = (p1 & 3) ^ SWZ(r1);
    const _Float16* gA0 = A  + (size_t)(m0 + r0) * CIN + c0g * 8;
    const _Float16* gA1 = A  + (size_t)(m0 + r1) * CIN + c1g * 8;
    const _Float16* gB0 = Wm + (size_t)(n0 + r0) * CIN + c0g * 8;
    const _Float16* gB1 = Wm + (size_t)(n0 + r1) * CIN + c1g * 8;
    char* sA = (char*)lds.st.a;
    char* sB = (char*)lds.st.b;
    const unsigned d0 = (unsigned)(w * 64) * 16;
    const unsigned d1 = (unsigned)(256 + w * 64) * 16;

    // fragment read offsets (A: m=lane&15, k=(lane>>4)*8+j; B mirrors with n)
    const int wm = (w >> 1) * 64, wn = (w & 1) * 64;
    const int mrow = lane & 15, kc = lane >> 4;
    const int sw = kc ^ SWZ(mrow);
    unsigned offA[4], offB[4];
#pragma unroll
    for (int i = 0; i < 4; ++i) {
        offA[i] = (unsigned)(((wm + i * 16 + mrow) * 4 + sw) * 16);
        offB[i] = (unsigned)(((wn + i * 16 + mrow) * 4 + sw) * 16);
    }

    f32x4 acc[4][4] = {};
    for (int k0 = 0; k0 < CIN; k0 += 32) {
        __syncthreads();  // previous frag reads done before overwrite
        async16(sA + d0, gA0 + k0);
        async16(sA + d1, gA1 + k0);
        async16(sB + d0, gB0 + k0);
        async16(sB + d1, gB1 + k0);
        __syncthreads();  // staging complete (vmcnt(0) drained by compiler)

        half8 av[4], bv[4];
#pragma unroll
        for (int i = 0; i < 4; ++i) av[i] = *(const half8*)(sA + offA[i]);
#pragma unroll
        for (int j = 0; j < 4; ++j) bv[j] = *(const half8*)(sB + offB[j]);
#pragma unroll
        for (int i = 0; i < 4; ++i)
#pragma unroll
            for (int j = 0; j < 4; ++j)
                acc[i][j] = __builtin_amdgcn_mfma_f32_16x16x32_f16(
                    av[i], bv[j], acc[i][j], 0, 0, 0);
    }

    // C fragments -> LDS (C/D layout: col=lane&15, row=(lane>>4)*4+reg)
    __syncthreads();
    {
        const int rb = wm + (lane >> 4) * 4;
        const int cb = wn + (lane & 15);
#pragma unroll
        for (int i = 0; i < 4; ++i)
#pragma unroll
            for (int j = 0; j < 4; ++j)
#pragma unroll
                for (int r = 0; r < 4; ++r)
                    lds.c[(rb + i * 16 + r) * 132 + (cb + j * 16)] = acc[i][j][r];
    }
    __syncthreads();

    // LIF scan: thread j owns channel n0+j, sequential over t; pack spike bits
    if (tid < 128) {
        float scale = exp2f((float)scale_exp[n0 + tid]);
        float thr   = exp2f((float)thr_exp[0]);
        float a = 0.f;
        unsigned bits[4] = {0u, 0u, 0u, 0u};
#pragma unroll 4
        for (int t = 0; t < 128; ++t) {
            a += lds.c[t * 132 + tid] * scale;
            unsigned s = (a >= thr) ? 1u : 0u;
            if (s) a = 0.f;
            bits[t >> 5] |= s << (t & 31);
        }
#pragma unroll
        for (int q = 0; q < 4; ++q) pb[tid * 4 + q] = bits[q];
    }
    __syncthreads();

    // coalesced float4 output: out[b][n0+co][t]
    {
        const int t4 = tid & 31, cr = tid >> 5;
#pragma unroll
        for (int s2 = 0; s2 < 16; ++s2) {
            int co = s2 * 8 + cr;
            unsigned wb  = pb[co * 4 + (t4 >> 3)];
            unsigned nib = (wb >> ((t4 & 7) * 4)) & 0xFu;
            float4 v;
            v.x = (float)(nib & 1u);
            v.y = (float)((nib >> 1) & 1u);
            v.z = (float)((nib >> 2) & 1u);
            v.w = (float)((nib >> 3) & 1u);
            *(float4*)(out + (size_t)(b * COUT + n0 + co) * TT + t4 * 4) = v;
        }
    }
}

extern "C" void kernel_launch(void* const* d_in, const int* in_sizes, int n_in,
                              void* d_out, int out_size, void* d_ws, size_t ws_size,
                              hipStream_t stream) {
    const float* spikes   = (const float*)d_in[0];
    const float* weights  = (const float*)d_in[1];
    const float* mask     = (const float*)d_in[2];
    const int*   scale_e  = (const int*)d_in[3];
    const int*   thr_e    = (const int*)d_in[4];
    float* out = (float*)d_out;

    // workspace: A fp16 [8192][2048] = 32 MB, Wm fp16 [2048][2048] = 8 MB
    _Float16* Abf = (_Float16*)d_ws;
    _Float16* Wm  = (_Float16*)((char*)d_ws + (size_t)BB * TT * CIN * sizeof(_Float16));

    prep_w_kernel<<<(COUT * CIN) / (256 * 8), 256, 0, stream>>>(weights, mask, Wm);
    prep_a_kernel<<<BB * 4 * 32, 256, 0, stream>>>(spikes, Abf);
    snn_gemm_scan<<<BB * (COUT / 128), 256, 0, stream>>>(Abf, Wm, scale_e, thr_e, out);
}

// Round 2
// 190.522 us; speedup vs baseline: 1.2785x; 1.2785x over previous
//
#include <hip/hip_runtime.h>
#include <hip/hip_bf16.h>

// Problem constants (match reference setup_inputs)
#define BB   64
#define CIN  2048
#define COUT 2048
#define TT   128

typedef int i32x4 __attribute__((ext_vector_type(4)));

// XOR swizzle of 16B chunks within a 64B row: keeps global_load_lds staging
// (wave-uniform base + lane*16, no padding allowed) compatible with
// conflict-light ds_read_b128 fragment reads (2-way = free on gfx950).
#define SWZ(r) ((((r) & 3) ^ (((r) >> 2) & 3)))

__device__ __forceinline__ void async16(char* lds_dst, const char* g_src) {
    __builtin_amdgcn_global_load_lds(
        (const __attribute__((address_space(1))) void*)g_src,
        (__attribute__((address_space(3))) void*)lds_dst,
        16, 0, 0);
}

// --- Fused prep: masked weights -> i8 [COUT][CIN], spikes -> i8 A[(b*T+t)][c]
__global__ void prep_kernel(const float* __restrict__ spikes,
                            const float* __restrict__ w,
                            const float* __restrict__ msk,
                            char* __restrict__ A,
                            char* __restrict__ Wm) {
    __shared__ float tile[64][33];
    int bid = blockIdx.x;
    int tid = threadIdx.x;

    if (bid < 1024) {
        // weights: 16 elements/thread, exact int8 cast of w*mask
        size_t i = ((size_t)bid * 256 + tid) * 16;
        int out4[4];
#pragma unroll
        for (int q = 0; q < 4; ++q) {
            float4 a = *(const float4*)(w + i + q * 4);
            float4 m = *(const float4*)(msk + i + q * 4);
            int b0 = (int)(char)(int)(a.x * m.x);
            int b1 = (int)(char)(int)(a.y * m.y);
            int b2 = (int)(char)(int)(a.z * m.z);
            int b3 = (int)(char)(int)(a.w * m.w);
            out4[q] = (b0 & 0xFF) | ((b1 & 0xFF) << 8) | ((b2 & 0xFF) << 16) | (b3 << 24);
        }
        *(int4*)(Wm + i) = *(int4*)out4;
        return;
    }

    // spikes [B][C][T] fp32 -> A[(b*T+t)][c] i8 via LDS transpose
    bid -= 1024;
    int cc = bid & 31;          // c-tile: 64 channels
    int tt = (bid >> 5) & 3;    // t-tile: 32 timesteps
    int b  = bid >> 7;
    int c0 = cc * 64, t0 = tt * 32;

    int t  = tid & 31;
    int c8 = tid >> 5;          // 0..7
#pragma unroll
    for (int s = 0; s < 8; ++s) {
        int c = s * 8 + c8;
        tile[c][t] = spikes[((size_t)b * CIN + c0 + c) * TT + t0 + t];
    }
    __syncthreads();

    int tw_ = tid >> 4;         // 0..15
    int cq  = tid & 15;
#pragma unroll
    for (int s2 = 0; s2 < 2; ++s2) {
        int tw = tw_ + s2 * 16;
        int packed = 0;
#pragma unroll
        for (int q = 0; q < 4; ++q)
            packed |= ((tile[cq * 4 + q][tw] != 0.f) ? 1 : 0) << (8 * q);
        *(int*)(A + ((size_t)(b * TT) + t0 + tw) * CIN + c0 + cq * 4) = packed;
    }
}

// --- Fused GEMM (128x128 tile, BK=64, mfma_i32_16x16x64_i8, exact)
//     + LIF scan epilogue in two 64-channel passes + coalesced store ---
__global__ void __launch_bounds__(256, 3)
snn_gemm_scan(const char* __restrict__ A,    // [8192][2048] i8
              const char* __restrict__ Wm,   // [2048][2048] i8
              const int* __restrict__ scale_exp,
              const int* __restrict__ thr_exp,
              float* __restrict__ out) {     // [B][COUT][T]
    __shared__ __align__(16) union {
        struct { char a[128 * 64]; char b[128 * 64]; } st;  // 16 KB
        float c[128 * 68];                                  // 34.8 KB
    } lds;
    __shared__ unsigned pb[64 * 4];

    const int tid  = threadIdx.x;
    const int lane = tid & 63;
    const int w    = tid >> 6;

    // XCD-aware swizzle: blocks on one XCD share b -> A-tile L2 reuse
    int flat = blockIdx.x;
    int xcd = flat & 7, idx = flat >> 3;
    int b  = xcd * 8 + (idx >> 4);
    int n0 = (idx & 15) * 128;
    int m0 = b * TT;

    // staging: 512 chunks of 16B per operand tile, 2 per thread, swizzled
    int r0 = tid >> 2, cl = tid & 3;
    int r1 = r0 + 64;
    int cg = cl ^ SWZ(r0);      // SWZ(r1)==SWZ(r0)
    const char* gA0 = A  + (size_t)(m0 + r0) * CIN + cg * 16;
    const char* gA1 = A  + (size_t)(m0 + r1) * CIN + cg * 16;
    const char* gB0 = Wm + (size_t)(n0 + r0) * CIN + cg * 16;
    const char* gB1 = Wm + (size_t)(n0 + r1) * CIN + cg * 16;
    char* sA = (char*)lds.st.a;
    char* sB = (char*)lds.st.b;
    const unsigned d0 = (unsigned)(w * 64) * 16;          // wave-uniform dests
    const unsigned d1 = (unsigned)(256 + w * 64) * 16;

    // fragment offsets: A[m=lane&15][k = (lane>>4)*16 + byte], one b128 per frag
    const int wm = (w >> 1) * 64, wn = (w & 1) * 64;
    const int mrow = lane & 15, kc = lane >> 4;
    const int sw = kc ^ SWZ(mrow);
    unsigned offA[4], offB[4];
#pragma unroll
    for (int i = 0; i < 4; ++i) {
        offA[i] = (unsigned)(((wm + i * 16 + mrow) * 4 + sw) * 16);
        offB[i] = (unsigned)(((wn + i * 16 + mrow) * 4 + sw) * 16);
    }

    i32x4 acc[4][4] = {};
    for (int k0 = 0; k0 < CIN; k0 += 64) {
        __syncthreads();  // previous frag reads done before overwrite
        async16(sA + d0, gA0 + k0);
        async16(sA + d1, gA1 + k0);
        async16(sB + d0, gB0 + k0);
        async16(sB + d1, gB1 + k0);
        __syncthreads();  // staging complete

        i32x4 av[4], bv[4];
#pragma unroll
        for (int i = 0; i < 4; ++i) av[i] = *(const i32x4*)(sA + offA[i]);
#pragma unroll
        for (int j = 0; j < 4; ++j) bv[j] = *(const i32x4*)(sB + offB[j]);
#pragma unroll
        for (int i = 0; i < 4; ++i)
#pragma unroll
            for (int j = 0; j < 4; ++j)
                acc[i][j] = __builtin_amdgcn_mfma_i32_16x16x64_i8(
                    av[i], bv[j], acc[i][j], 0, 0, 0);
    }

    const float thr = exp2f((float)thr_exp[0]);

    // Epilogue: two passes of 64 channels (keeps LDS at ~36 KB -> 3+ blocks/CU)
#pragma unroll
    for (int p = 0; p < 2; ++p) {
        __syncthreads();
        if ((w & 1) == p) {
            const int rb = (lane >> 4) * 4;
            const int cb = lane & 15;
#pragma unroll
            for (int i = 0; i < 4; ++i)
#pragma unroll
                for (int j = 0; j < 4; ++j)
#pragma unroll
                    for (int r = 0; r < 4; ++r)
                        lds.c[(wm + i * 16 + rb + r) * 68 + (j * 16 + cb)] =
                            (float)acc[i][j][r];
        }
        __syncthreads();

        if (tid < 64) {
            float scale = exp2f((float)scale_exp[n0 + p * 64 + tid]);
            float a = 0.f;
            unsigned bits[4] = {0u, 0u, 0u, 0u};
#pragma unroll 4
            for (int t = 0; t < 128; ++t) {
                a += lds.c[t * 68 + tid] * scale;
                unsigned s = (a >= thr) ? 1u : 0u;
                if (s) a = 0.f;
                bits[t >> 5] |= s << (t & 31);
            }
#pragma unroll
            for (int q = 0; q < 4; ++q) pb[tid * 4 + q] = bits[q];
        }
        __syncthreads();

        // coalesced float4 stores: out[b][n0 + p*64 + co][t]
        const int t4 = tid & 31, cr = tid >> 5;
#pragma unroll
        for (int s2 = 0; s2 < 8; ++s2) {
            int co = s2 * 8 + cr;
            unsigned wb  = pb[co * 4 + (t4 >> 3)];
            unsigned nib = (wb >> ((t4 & 7) * 4)) & 0xFu;
            float4 v;
            v.x = (float)(nib & 1u);
            v.y = (float)((nib >> 1) & 1u);
            v.z = (float)((nib >> 2) & 1u);
            v.w = (float)((nib >> 3) & 1u);
            *(float4*)(out + (size_t)(b * COUT + n0 + p * 64 + co) * TT + t4 * 4) = v;
        }
    }
}

extern "C" void kernel_launch(void* const* d_in, const int* in_sizes, int n_in,
                              void* d_out, int out_size, void* d_ws, size_t ws_size,
                              hipStream_t stream) {
    const float* spikes  = (const float*)d_in[0];
    const float* weights = (const float*)d_in[1];
    const float* mask    = (const float*)d_in[2];
    const int*   scale_e = (const int*)d_in[3];
    const int*   thr_e   = (const int*)d_in[4];
    float* out = (float*)d_out;

    // workspace: A i8 [8192][2048] = 16 MB, Wm i8 [2048][2048] = 4 MB
    char* Ai8 = (char*)d_ws;
    char* Wm  = (char*)d_ws + (size_t)BB * TT * CIN;

    prep_kernel<<<1024 + BB * 4 * 32, 256, 0, stream>>>(spikes, weights, mask, Ai8, Wm);
    snn_gemm_scan<<<BB * (COUT / 128), 256, 0, stream>>>(Ai8, Wm, scale_e, thr_e, out);
}

// Round 3
// 183.526 us; speedup vs baseline: 1.3272x; 1.0381x over previous
//
#include <hip/hip_runtime.h>
#include <hip/hip_bf16.h>

// Problem constants (match reference setup_inputs)
#define BB   64
#define CIN  2048
#define COUT 2048
#define TT   128

typedef int i32x4 __attribute__((ext_vector_type(4)));

__device__ __forceinline__ void async16(char* lds_dst, const char* g_src) {
    __builtin_amdgcn_global_load_lds(
        (const __attribute__((address_space(1))) void*)g_src,
        (__attribute__((address_space(3))) void*)lds_dst,
        16, 0, 0);
}

// --- Fused prep: masked weights -> i8 [COUT][CIN], spikes -> i8 A[(b*T+t)][c]
__global__ void prep_kernel(const float* __restrict__ spikes,
                            const float* __restrict__ w,
                            const float* __restrict__ msk,
                            char* __restrict__ A,
                            char* __restrict__ Wm) {
    __shared__ float tile[64][33];
    int bid = blockIdx.x;
    int tid = threadIdx.x;

    if (bid < 1024) {
        // weights: 16 elements/thread, exact int8 cast of w*mask
        size_t i = ((size_t)bid * 256 + tid) * 16;
        int out4[4];
#pragma unroll
        for (int q = 0; q < 4; ++q) {
            float4 a = *(const float4*)(w + i + q * 4);
            float4 m = *(const float4*)(msk + i + q * 4);
            int b0 = (int)(char)(int)(a.x * m.x);
            int b1 = (int)(char)(int)(a.y * m.y);
            int b2 = (int)(char)(int)(a.z * m.z);
            int b3 = (int)(char)(int)(a.w * m.w);
            out4[q] = (b0 & 0xFF) | ((b1 & 0xFF) << 8) | ((b2 & 0xFF) << 16) | (b3 << 24);
        }
        *(int4*)(Wm + i) = *(int4*)out4;
        return;
    }

    // spikes [B][C][T] fp32 -> A[(b*T+t)][c] i8 via LDS transpose
    bid -= 1024;
    int cc = bid & 31;          // c-tile: 64 channels
    int tt = (bid >> 5) & 3;    // t-tile: 32 timesteps
    int b  = bid >> 7;
    int c0 = cc * 64, t0 = tt * 32;

    // float4 reads: 8 lanes cover one 128-B channel row; wave = 8 rows
    int t4 = tid & 7;           // float4 slot along t
    int cr = tid >> 3;          // 0..31
#pragma unroll
    for (int s = 0; s < 2; ++s) {
        int c = cr + s * 32;
        float4 v = *(const float4*)(spikes + ((size_t)b * CIN + c0 + c) * TT + t0 + t4 * 4);
        tile[c][t4 * 4 + 0] = v.x;
        tile[c][t4 * 4 + 1] = v.y;
        tile[c][t4 * 4 + 2] = v.z;
        tile[c][t4 * 4 + 3] = v.w;
    }
    __syncthreads();

    int tw_ = tid >> 4;         // 0..15
    int cq  = tid & 15;
#pragma unroll
    for (int s2 = 0; s2 < 2; ++s2) {
        int tw = tw_ + s2 * 16;
        int packed = 0;
#pragma unroll
        for (int q = 0; q < 4; ++q)
            packed |= ((tile[cq * 4 + q][tw] != 0.f) ? 1 : 0) << (8 * q);
        *(int*)(A + ((size_t)(b * TT) + t0 + tw) * CIN + c0 + cq * 4) = packed;
    }
}

// --- Fused GEMM (128x128 tile, BK=128, mfma_i32_16x16x64_i8, exact)
//     + LIF scan epilogue in two 64-channel passes + coalesced store ---
__global__ void __launch_bounds__(256, 4)
snn_gemm_scan(const char* __restrict__ A,    // [8192][2048] i8
              const char* __restrict__ Wm,   // [2048][2048] i8
              const int* __restrict__ scale_exp,
              const int* __restrict__ thr_exp,
              float* __restrict__ out) {     // [B][COUT][T]
    __shared__ __align__(16) union {
        struct { char a[128 * 128]; char b[128 * 128]; } st;  // 32 KB
        float c[128 * 68];                                    // 34.8 KB
    } lds;
    __shared__ unsigned pb[64 * 4];

    const int tid  = threadIdx.x;
    const int lane = tid & 63;
    const int w    = tid >> 6;

    // XCD-aware swizzle: blocks on one XCD share b -> A-tile L2 reuse
    int flat = blockIdx.x;
    int xcd = flat & 7, idx = flat >> 3;
    int b  = xcd * 8 + (idx >> 4);
    int n0 = (idx & 15) * 128;
    int m0 = b * TT;

    // staging: rows of 128 B = 8 chunks of 16 B; global column XOR-swizzled
    // (col ^= row&7) so LDS placement stays linear (global_load_lds constraint)
    // while fragment ds_read_b128 lands 2-way (free) on banks.
    int rr = tid >> 3;               // base row 0..31 (+32 per round)
    int cg = (tid & 7) ^ (rr & 7);   // swizzled global chunk col (round-invar)
    const char* gAt = A  + (size_t)(m0 + rr) * CIN + cg * 16;
    const char* gBt = Wm + (size_t)(n0 + rr) * CIN + cg * 16;
    char* sA = (char*)lds.st.a;
    char* sB = (char*)lds.st.b;

    // fragment byte offsets (s=0); s=1 is off ^ 64 (col-chunk bit2 = s)
    const int wm = (w >> 1) * 64, wn = (w & 1) * 64;
    const int mrow = lane & 15, kc = lane >> 4;
    unsigned offA[4], offB[4];
#pragma unroll
    for (int i = 0; i < 4; ++i) {
        offA[i] = (unsigned)(((wm + i * 16 + mrow) * 8 + (kc ^ (mrow & 7))) * 16);
        offB[i] = (unsigned)(((wn + i * 16 + mrow) * 8 + (kc ^ (mrow & 7))) * 16);
    }

    i32x4 acc[4][4] = {};
    for (int k0 = 0; k0 < CIN; k0 += 128) {
        __syncthreads();  // previous frag reads done before overwrite
#pragma unroll
        for (int i = 0; i < 4; ++i) {
            async16(sA + (unsigned)(tid + 256 * i) * 16, gAt + k0 + (size_t)(32 * i) * CIN);
            async16(sB + (unsigned)(tid + 256 * i) * 16, gBt + k0 + (size_t)(32 * i) * CIN);
        }
        __syncthreads();  // staging complete

#pragma unroll
        for (int s = 0; s < 2; ++s) {
            const unsigned sx = (unsigned)(s * 64);
            i32x4 av[4], bv[4];
#pragma unroll
            for (int i = 0; i < 4; ++i) av[i] = *(const i32x4*)(sA + (offA[i] ^ sx));
#pragma unroll
            for (int j = 0; j < 4; ++j) bv[j] = *(const i32x4*)(sB + (offB[j] ^ sx));
#pragma unroll
            for (int i = 0; i < 4; ++i)
#pragma unroll
                for (int j = 0; j < 4; ++j)
                    acc[i][j] = __builtin_amdgcn_mfma_i32_16x16x64_i8(
                        av[i], bv[j], acc[i][j], 0, 0, 0);
        }
    }

    const float thr = exp2f((float)thr_exp[0]);

    // Epilogue: two passes of 64 channels (keeps LDS at ~36 KB -> 4 blocks/CU)
#pragma unroll
    for (int p = 0; p < 2; ++p) {
        __syncthreads();
        if ((w & 1) == p) {
            const int rb = (lane >> 4) * 4;
            const int cb = lane & 15;
#pragma unroll
            for (int i = 0; i < 4; ++i)
#pragma unroll
                for (int j = 0; j < 4; ++j)
#pragma unroll
                    for (int r = 0; r < 4; ++r)
                        lds.c[(wm + i * 16 + rb + r) * 68 + (j * 16 + cb)] =
                            (float)acc[i][j][r];
        }
        __syncthreads();

        if (tid < 64) {
            float scale = exp2f((float)scale_exp[n0 + p * 64 + tid]);
            float a = 0.f;
            unsigned bits[4] = {0u, 0u, 0u, 0u};
#pragma unroll 4
            for (int t = 0; t < 128; ++t) {
                a += lds.c[t * 68 + tid] * scale;
                unsigned s = (a >= thr) ? 1u : 0u;
                if (s) a = 0.f;
                bits[t >> 5] |= s << (t & 31);
            }
#pragma unroll
            for (int q = 0; q < 4; ++q) pb[tid * 4 + q] = bits[q];
        }
        __syncthreads();

        // coalesced float4 stores: out[b][n0 + p*64 + co][t]
        const int t4 = tid & 31, cr = tid >> 5;
#pragma unroll
        for (int s2 = 0; s2 < 8; ++s2) {
            int co = s2 * 8 + cr;
            unsigned wb  = pb[co * 4 + (t4 >> 3)];
            unsigned nib = (wb >> ((t4 & 7) * 4)) & 0xFu;
            float4 v;
            v.x = (float)(nib & 1u);
            v.y = (float)((nib >> 1) & 1u);
            v.z = (float)((nib >> 2) & 1u);
            v.w = (float)((nib >> 3) & 1u);
            *(float4*)(out + (size_t)(b * COUT + n0 + p * 64 + co) * TT + t4 * 4) = v;
        }
    }
}

extern "C" void kernel_launch(void* const* d_in, const int* in_sizes, int n_in,
                              void* d_out, int out_size, void* d_ws, size_t ws_size,
                              hipStream_t stream) {
    const float* spikes  = (const float*)d_in[0];
    const float* weights = (const float*)d_in[1];
    const float* mask    = (const float*)d_in[2];
    const int*   scale_e = (const int*)d_in[3];
    const int*   thr_e   = (const int*)d_in[4];
    float* out = (float*)d_out;

    // workspace: A i8 [8192][2048] = 16 MB, Wm i8 [2048][2048] = 4 MB
    char* Ai8 = (char*)d_ws;
    char* Wm  = (char*)d_ws + (size_t)BB * TT * CIN;

    prep_kernel<<<1024 + BB * 4 * 32, 256, 0, stream>>>(spikes, weights, mask, Ai8, Wm);
    snn_gemm_scan<<<BB * (COUT / 128), 256, 0, stream>>>(Ai8, Wm, scale_e, thr_e, out);
}